// Round 13
// baseline (173.919 us; speedup 1.0000x reference)
//
#include <hip/hip_runtime.h>

static constexpr int C    = 64;
static constexpr int H    = 128;
static constexpr int W    = 128;
static constexpr int NPIX = H * W;      // 16384
static constexpr int PAD  = 3;          // WS=7 -> +-3

typedef float vf4 __attribute__((ext_vector_type(4)));   // NT-store-able

// ---------------------------------------------------------------------------
// 1) conv1x1, LDS-staged-x version. [r12 exact]
// ---------------------------------------------------------------------------
__global__ __launch_bounds__(256, 4) void k_conv(
    const float* __restrict__ x,
    const float* __restrict__ Wq, const float* __restrict__ bq,
    const float* __restrict__ Wk, const float* __restrict__ bk,
    const float* __restrict__ Wv, const float* __restrict__ bv,
    float* __restrict__ qT, float* __restrict__ ko, float* __restrict__ vo)
{
    __shared__ float xs[64][64];         // 16 KB
    const int tid  = threadIdx.x;
    const int lane = tid & 63;
    const int p0   = blockIdx.x * 64;
    const int p    = p0 + lane;
    const int o0   = __builtin_amdgcn_readfirstlane(
                         blockIdx.y * 16 + (tid >> 6) * 4);

#pragma unroll
    for (int r = 0; r < 4; ++r) {
        int f  = tid + r * 256;          // 0..1023
        int c  = f >> 4;                 // 16 float4 per channel row
        int i4 = (f & 15) << 2;
        *(float4*)(&xs[c][i4]) =
            *(const float4*)(x + (size_t)c * NPIX + p0 + i4);
    }
    __syncthreads();

    float aq[4], ak[4], av[4];
#pragma unroll
    for (int j = 0; j < 4; ++j) {
        aq[j] = bq[o0 + j];
        ak[j] = bk[o0 + j];
        av[j] = bv[o0 + j];
    }

#pragma unroll
    for (int c = 0; c < C; ++c) {
        const float xv = xs[c][lane];    // ds_read_b32, conflict-free
#pragma unroll
        for (int j = 0; j < 4; ++j) {
            aq[j] += Wq[(o0 + j) * C + c] * xv;   // W: wave-uniform s_load
            ak[j] += Wk[(o0 + j) * C + c] * xv;
            av[j] += Wv[(o0 + j) * C + c] * xv;
        }
    }

    vf4 qv4 = { aq[0], aq[1], aq[2], aq[3] };
    __builtin_nontemporal_store(qv4, (vf4*)(qT + (size_t)p * C + o0));
#pragma unroll
    for (int j = 0; j < 4; ++j) {
        __builtin_nontemporal_store(ak[j], ko + (size_t)(o0 + j) * NPIX + p);
        __builtin_nontemporal_store(av[j], vo + (size_t)(o0 + j) * NPIX + p);
    }
}

// ---------------------------------------------------------------------------
// 2) merged dispatch: [gram+diag] + [7x7 box of v]. [r12 logic, but
//    MEASUREMENT ROUND: grid = 4 x 1536, bid = blockIdx.x % 1536 -> each
//    logical block executed 4x (identical writes, race-benign). Each k_mid
//    dispatch now ~4*Tm, surfacing it above the 45us fills in the top-5
//    counter table WITH its PMC row. dur/4 = Tm; total delta = 3*Tm.
// ---------------------------------------------------------------------------
__global__ __launch_bounds__(256, 3) void k_mid(
    const float* __restrict__ qT, const float* __restrict__ kmat,
    const float* __restrict__ v,
    float* __restrict__ Sd, float* __restrict__ Vs)
{
    __shared__ union {
        struct { float Sl[22][130]; float qs[22][64]; } g;   // 16.7 KB
        struct { float vt[22][128]; float vh[22][128]; } box; // 22.5 KB
    } u;
    const int bid = blockIdx.x % 1536;   // 4 copies of each logical block
    const int tid = threadIdx.x;

    if (bid < 1024) {
        // ----- fused row-Gram + diagonal 7-sum -----
        const int h   = bid >> 3;
        const int w0  = (bid & 7) * 16;

        // stage q rows w0-3 .. w0+18 (zero-filled outside [0,W))
        for (int i = tid; i < 22 * 16; i += 256) {
            int r  = i >> 4, c4 = (i & 15) << 2;
            int wp = w0 - 3 + r;
            float4 qv = make_float4(0.f, 0.f, 0.f, 0.f);
            if (wp >= 0 && wp < W)
                qv = *(const float4*)(qT + (size_t)(h * W + wp) * C + c4);
            *(float4*)(&u.g.qs[r][c4]) = qv;
        }

        // two k-columns per thread: kkt and kkt+64 (coalesced loads)
        const int kkt = tid & 63;
        const int g   = tid >> 6;            // 0..3, wave-uniform row group
        float ks0[C], ks1[C];
#pragma unroll
        for (int c = 0; c < C; ++c) {
            ks0[c] = kmat[c * NPIX + h * W + kkt];
            ks1[c] = kmat[c * NPIX + h * W + kkt + 64];
        }
        __syncthreads();

        for (int j = 0; j < 6; ++j) {
            int row = g * 6 + j;             // 0..23, wave-uniform
            if (row < 22) {                  // wave-uniform branch
                float a0 = 0.f, a1 = 0.f, a2 = 0.f, a3 = 0.f;
                float b0 = 0.f, b1 = 0.f, b2 = 0.f, b3 = 0.f;
#pragma unroll
                for (int c = 0; c < C; c += 4) {
                    float4 qv = *(const float4*)(&u.g.qs[row][c]); // broadcast
                    a0 += qv.x * ks0[c + 0];  b0 += qv.x * ks1[c + 0];
                    a1 += qv.y * ks0[c + 1];  b1 += qv.y * ks1[c + 1];
                    a2 += qv.z * ks0[c + 2];  b2 += qv.z * ks1[c + 2];
                    a3 += qv.w * ks0[c + 3];  b3 += qv.w * ks1[c + 3];
                }
                u.g.Sl[row][kkt]      = (a0 + a1) + (a2 + a3);
                u.g.Sl[row][kkt + 64] = (b0 + b1) + (b2 + b3);
            }
        }
        __syncthreads();

        // ----- diagonal 7-sum (unchanged) -----
        const int kk  = tid & 127;
        const int wsl = tid >> 7;            // 0/1, wave-uniform
#pragma unroll
        for (int r = 0; r < 8; ++r) {
            int wl = wsl * 8 + r;            // 0..15
            float a = 0.f;
#pragma unroll
            for (int dd = -PAD; dd <= PAD; ++dd) {
                int kj = kk + dd;
                if (kj >= 0 && kj < W)
                    a += u.g.Sl[wl + 3 + dd][kj];
            }
            Sd[(size_t)(h * W + w0 + wl) * W + kk] = a;
        }
    } else {
        // ----- 7x7 box sum of v (separable in LDS, unchanged) -----
        const int b2 = bid - 1024;           // 0..511
        const int c  = b2 >> 3;              // 0..63
        const int h0 = (b2 & 7) * 16;

        for (int i = tid; i < 22 * 128; i += 256) {
            int r = i >> 7, w = i & 127;
            int h = h0 - 3 + r;
            u.box.vt[r][w] = (h >= 0 && h < H) ? v[c * NPIX + h * W + w] : 0.f;
        }
        __syncthreads();
        for (int i = tid; i < 22 * 128; i += 256) {
            int r = i >> 7, w = i & 127;
            float s = 0.f;
#pragma unroll
            for (int d = -PAD; d <= PAD; ++d) {
                int wj = w + d;
                if (wj >= 0 && wj < W) s += u.box.vt[r][wj];
            }
            u.box.vh[r][w] = s;
        }
        __syncthreads();
        for (int i = tid; i < 16 * 128; i += 256) {
            int r = i >> 7, w = i & 127;
            float s = 0.f;
#pragma unroll
            for (int d = 0; d < 7; ++d) s += u.box.vh[r + d][w];
            Vs[c * NPIX + (h0 + r) * W + w] = s;
        }
    }
}

// ---------------------------------------------------------------------------
// 3) FUSED vertical-7-sum + softmax + PV, V-from-global. [r12 exact]
// ---------------------------------------------------------------------------
__global__ __launch_bounds__(1024, 4) void k_fused(
    const float* __restrict__ Sd, const float* __restrict__ Vs,
    float* __restrict__ out)
{
    constexpr int AP = 129;          // attn LDS pitch
    __shared__ float At[64][AP];     // attn[w-local][kk], 33.0 KB

    const int h   = blockIdx.x;
    const int w0  = blockIdx.y * 64;
    const int tid = threadIdx.x;

    // ---- phase A: logits (vertical 7-sum of Sd) + softmax into LDS ----
    const int wl = tid >> 4;             // 0..63 (w within half)
    const int s  = tid & 15;             // kk-16th: kk = s*8 + e

    float4 g0 = make_float4(0.f, 0.f, 0.f, 0.f);
    float4 g1 = g0;
#pragma unroll
    for (int i = 0; i < 7; ++i) {
        int hp = h - 3 + i;              // block-uniform branch
        if (hp >= 0 && hp < H) {
            const float4* src = (const float4*)(
                Sd + (size_t)hp * NPIX + (w0 + wl) * W + s * 8);
            float4 a = src[0], b = src[1];
            g0.x += a.x; g0.y += a.y; g0.z += a.z; g0.w += a.w;
            g1.x += b.x; g1.y += b.y; g1.z += b.z; g1.w += b.w;
        }
    }

    float lg[8] = { g0.x, g0.y, g0.z, g0.w,  g1.x, g1.y, g1.z, g1.w };

    float m = lg[0];
#pragma unroll
    for (int e = 1; e < 8; ++e) m = fmaxf(m, lg[e]);
#pragma unroll
    for (int off = 1; off <= 8; off <<= 1) m = fmaxf(m, __shfl_xor(m, off));

    float ssum = 0.f;
#pragma unroll
    for (int e = 0; e < 8; ++e) { lg[e] = __expf(lg[e] - m); ssum += lg[e]; }
#pragma unroll
    for (int off = 1; off <= 8; off <<= 1) ssum += __shfl_xor(ssum, off);
    const float inv = 1.f / ssum;

#pragma unroll
    for (int e = 0; e < 8; ++e) At[wl][s * 8 + e] = lg[e] * inv;

    __syncthreads();

    // ---- phase B: out[c, h, w0+w2] = sum_kk At[w2][kk] * Vs[c][h][kk] ----
    const int w2 = tid & 63;
    const int c0 = __builtin_amdgcn_readfirstlane((tid >> 6) * 4);

    const float* __restrict__ vr0 = Vs + (size_t)(c0 + 0) * NPIX + h * W;
    const float* __restrict__ vr1 = Vs + (size_t)(c0 + 1) * NPIX + h * W;
    const float* __restrict__ vr2 = Vs + (size_t)(c0 + 2) * NPIX + h * W;
    const float* __restrict__ vr3 = Vs + (size_t)(c0 + 3) * NPIX + h * W;

    float acc[4];
#pragma unroll
    for (int j = 0; j < 4; ++j) acc[j] = 0.f;

#pragma unroll 4
    for (int kk = 0; kk < 128; kk += 4) {
        float4 a  = *(const float4*)(&At[w2][kk]);        // only LDS read
        float4 v0 = *(const float4*)(vr0 + kk);           // uniform loads
        float4 v1 = *(const float4*)(vr1 + kk);
        float4 v2 = *(const float4*)(vr2 + kk);
        float4 v3 = *(const float4*)(vr3 + kk);
        acc[0] += a.x * v0.x + a.y * v0.y + a.z * v0.z + a.w * v0.w;
        acc[1] += a.x * v1.x + a.y * v1.y + a.z * v1.z + a.w * v1.w;
        acc[2] += a.x * v2.x + a.y * v2.y + a.z * v2.z + a.w * v2.w;
        acc[3] += a.x * v3.x + a.y * v3.y + a.z * v3.z + a.w * v3.w;
    }

#pragma unroll
    for (int j = 0; j < 4; ++j)
        out[(size_t)(c0 + j) * NPIX + h * W + w0 + w2] = acc[j];
}

// ---------------------------------------------------------------------------
// Workspace: 6M floats = 24 MB used, non-overlapping:
//   qT [0,1M)  k [1M,2M)  v [2M,3M)  Sd [3M,5M)  Vs [5M,6M)
// ---------------------------------------------------------------------------
extern "C" void kernel_launch(void* const* d_in, const int* in_sizes, int n_in,
                              void* d_out, int out_size, void* d_ws, size_t ws_size,
                              hipStream_t stream)
{
    const float* x  = (const float*)d_in[0];
    const float* Wq = (const float*)d_in[1];
    const float* bq = (const float*)d_in[2];
    const float* Wk = (const float*)d_in[3];
    const float* bk = (const float*)d_in[4];
    const float* Wv = (const float*)d_in[5];
    const float* bv = (const float*)d_in[6];
    float* out = (float*)d_out;

    float* ws = (float*)d_ws;
    const size_t NQ = (size_t)C * NPIX;       // 1M floats
    const size_t NS = (size_t)H * W * W;      // 2M floats

    float* qT   = ws;
    float* k    = ws + NQ;
    float* v    = ws + 2 * NQ;
    float* Sd   = ws + 3 * NQ;
    float* Vsum = ws + 3 * NQ + NS;

    k_conv<<<dim3(NPIX / 64, 4), 256, 0, stream>>>(x, Wq, bq, Wk, bk, Wv, bv, qT, k, v);
    // MEASUREMENT: 4x replicated k_mid (idempotent) -> visible in top-5 PMC
    k_mid<<<dim3(4 * 1536), 256, 0, stream>>>(qT, k, v, Sd, Vsum);
    k_fused<<<dim3(H, 2), 1024, 0, stream>>>(Sd, Vsum, out);
}

// Round 14
// 155.097 us; speedup vs baseline: 1.1214x; 1.1214x over previous
//
#include <hip/hip_runtime.h>

static constexpr int C    = 64;
static constexpr int H    = 128;
static constexpr int W    = 128;
static constexpr int NPIX = H * W;      // 16384
static constexpr int PAD  = 3;          // WS=7 -> +-3

typedef float vf4 __attribute__((ext_vector_type(4)));   // NT-store-able

// ---------------------------------------------------------------------------
// 1) conv1x1, LDS-staged-x. [r12 logic; MEASUREMENT: 4x replicated,
//    bx = blockIdx.x & 255 -> idempotent rewrites; dur/4 = Tc with PMC]
// ---------------------------------------------------------------------------
__global__ __launch_bounds__(256, 4) void k_conv(
    const float* __restrict__ x,
    const float* __restrict__ Wq, const float* __restrict__ bq,
    const float* __restrict__ Wk, const float* __restrict__ bk,
    const float* __restrict__ Wv, const float* __restrict__ bv,
    float* __restrict__ qT, float* __restrict__ ko, float* __restrict__ vo)
{
    __shared__ float xs[64][64];         // 16 KB
    const int tid  = threadIdx.x;
    const int lane = tid & 63;
    const int bx   = blockIdx.x & 255;   // 4 copies of each logical block
    const int p0   = bx * 64;
    const int p    = p0 + lane;
    const int o0   = __builtin_amdgcn_readfirstlane(
                         blockIdx.y * 16 + (tid >> 6) * 4);

#pragma unroll
    for (int r = 0; r < 4; ++r) {
        int f  = tid + r * 256;          // 0..1023
        int c  = f >> 4;                 // 16 float4 per channel row
        int i4 = (f & 15) << 2;
        *(float4*)(&xs[c][i4]) =
            *(const float4*)(x + (size_t)c * NPIX + p0 + i4);
    }
    __syncthreads();

    float aq[4], ak[4], av[4];
#pragma unroll
    for (int j = 0; j < 4; ++j) {
        aq[j] = bq[o0 + j];
        ak[j] = bk[o0 + j];
        av[j] = bv[o0 + j];
    }

#pragma unroll
    for (int c = 0; c < C; ++c) {
        const float xv = xs[c][lane];    // ds_read_b32, conflict-free
#pragma unroll
        for (int j = 0; j < 4; ++j) {
            aq[j] += Wq[(o0 + j) * C + c] * xv;   // W: wave-uniform s_load
            ak[j] += Wk[(o0 + j) * C + c] * xv;
            av[j] += Wv[(o0 + j) * C + c] * xv;
        }
    }

    vf4 qv4 = { aq[0], aq[1], aq[2], aq[3] };
    __builtin_nontemporal_store(qv4, (vf4*)(qT + (size_t)p * C + o0));
#pragma unroll
    for (int j = 0; j < 4; ++j) {
        __builtin_nontemporal_store(ak[j], ko + (size_t)(o0 + j) * NPIX + p);
        __builtin_nontemporal_store(av[j], vo + (size_t)(o0 + j) * NPIX + p);
    }
}

// ---------------------------------------------------------------------------
// 2) merged dispatch: [gram+diag] + [7x7 box of v]. [r12 exact, 1x]
// ---------------------------------------------------------------------------
__global__ __launch_bounds__(256, 3) void k_mid(
    const float* __restrict__ qT, const float* __restrict__ kmat,
    const float* __restrict__ v,
    float* __restrict__ Sd, float* __restrict__ Vs)
{
    __shared__ union {
        struct { float Sl[22][130]; float qs[22][64]; } g;   // 16.7 KB
        struct { float vt[22][128]; float vh[22][128]; } box; // 22.5 KB
    } u;
    const int bid = blockIdx.x;
    const int tid = threadIdx.x;

    if (bid < 1024) {
        // ----- fused row-Gram + diagonal 7-sum -----
        const int h   = bid >> 3;
        const int w0  = (bid & 7) * 16;

        // stage q rows w0-3 .. w0+18 (zero-filled outside [0,W))
        for (int i = tid; i < 22 * 16; i += 256) {
            int r  = i >> 4, c4 = (i & 15) << 2;
            int wp = w0 - 3 + r;
            float4 qv = make_float4(0.f, 0.f, 0.f, 0.f);
            if (wp >= 0 && wp < W)
                qv = *(const float4*)(qT + (size_t)(h * W + wp) * C + c4);
            *(float4*)(&u.g.qs[r][c4]) = qv;
        }

        // two k-columns per thread: kkt and kkt+64 (coalesced loads)
        const int kkt = tid & 63;
        const int g   = tid >> 6;            // 0..3, wave-uniform row group
        float ks0[C], ks1[C];
#pragma unroll
        for (int c = 0; c < C; ++c) {
            ks0[c] = kmat[c * NPIX + h * W + kkt];
            ks1[c] = kmat[c * NPIX + h * W + kkt + 64];
        }
        __syncthreads();

        for (int j = 0; j < 6; ++j) {
            int row = g * 6 + j;             // 0..23, wave-uniform
            if (row < 22) {                  // wave-uniform branch
                float a0 = 0.f, a1 = 0.f, a2 = 0.f, a3 = 0.f;
                float b0 = 0.f, b1 = 0.f, b2 = 0.f, b3 = 0.f;
#pragma unroll
                for (int c = 0; c < C; c += 4) {
                    float4 qv = *(const float4*)(&u.g.qs[row][c]); // broadcast
                    a0 += qv.x * ks0[c + 0];  b0 += qv.x * ks1[c + 0];
                    a1 += qv.y * ks0[c + 1];  b1 += qv.y * ks1[c + 1];
                    a2 += qv.z * ks0[c + 2];  b2 += qv.z * ks1[c + 2];
                    a3 += qv.w * ks0[c + 3];  b3 += qv.w * ks1[c + 3];
                }
                u.g.Sl[row][kkt]      = (a0 + a1) + (a2 + a3);
                u.g.Sl[row][kkt + 64] = (b0 + b1) + (b2 + b3);
            }
        }
        __syncthreads();

        // ----- diagonal 7-sum (unchanged) -----
        const int kk  = tid & 127;
        const int wsl = tid >> 7;            // 0/1, wave-uniform
#pragma unroll
        for (int r = 0; r < 8; ++r) {
            int wl = wsl * 8 + r;            // 0..15
            float a = 0.f;
#pragma unroll
            for (int dd = -PAD; dd <= PAD; ++dd) {
                int kj = kk + dd;
                if (kj >= 0 && kj < W)
                    a += u.g.Sl[wl + 3 + dd][kj];
            }
            Sd[(size_t)(h * W + w0 + wl) * W + kk] = a;
        }
    } else {
        // ----- 7x7 box sum of v (separable in LDS, unchanged) -----
        const int b2 = bid - 1024;           // 0..511
        const int c  = b2 >> 3;              // 0..63
        const int h0 = (b2 & 7) * 16;

        for (int i = tid; i < 22 * 128; i += 256) {
            int r = i >> 7, w = i & 127;
            int h = h0 - 3 + r;
            u.box.vt[r][w] = (h >= 0 && h < H) ? v[c * NPIX + h * W + w] : 0.f;
        }
        __syncthreads();
        for (int i = tid; i < 22 * 128; i += 256) {
            int r = i >> 7, w = i & 127;
            float s = 0.f;
#pragma unroll
            for (int d = -PAD; d <= PAD; ++d) {
                int wj = w + d;
                if (wj >= 0 && wj < W) s += u.box.vt[r][wj];
            }
            u.box.vh[r][w] = s;
        }
        __syncthreads();
        for (int i = tid; i < 16 * 128; i += 256) {
            int r = i >> 7, w = i & 127;
            float s = 0.f;
#pragma unroll
            for (int d = 0; d < 7; ++d) s += u.box.vh[r + d][w];
            Vs[c * NPIX + (h0 + r) * W + w] = s;
        }
    }
}

// ---------------------------------------------------------------------------
// 3) FUSED vertical-7-sum + softmax + PV, V-from-global. [r12 logic;
//    MEASUREMENT: 4x replicated, h = blockIdx.x & 127; dur/4 = Tf with PMC]
// ---------------------------------------------------------------------------
__global__ __launch_bounds__(1024, 4) void k_fused(
    const float* __restrict__ Sd, const float* __restrict__ Vs,
    float* __restrict__ out)
{
    constexpr int AP = 129;          // attn LDS pitch
    __shared__ float At[64][AP];     // attn[w-local][kk], 33.0 KB

    const int h   = blockIdx.x & 127;    // 4 copies of each logical block
    const int w0  = blockIdx.y * 64;
    const int tid = threadIdx.x;

    // ---- phase A: logits (vertical 7-sum of Sd) + softmax into LDS ----
    const int wl = tid >> 4;             // 0..63 (w within half)
    const int s  = tid & 15;             // kk-16th: kk = s*8 + e

    float4 g0 = make_float4(0.f, 0.f, 0.f, 0.f);
    float4 g1 = g0;
#pragma unroll
    for (int i = 0; i < 7; ++i) {
        int hp = h - 3 + i;              // block-uniform branch
        if (hp >= 0 && hp < H) {
            const float4* src = (const float4*)(
                Sd + (size_t)hp * NPIX + (w0 + wl) * W + s * 8);
            float4 a = src[0], b = src[1];
            g0.x += a.x; g0.y += a.y; g0.z += a.z; g0.w += a.w;
            g1.x += b.x; g1.y += b.y; g1.z += b.z; g1.w += b.w;
        }
    }

    float lg[8] = { g0.x, g0.y, g0.z, g0.w,  g1.x, g1.y, g1.z, g1.w };

    float m = lg[0];
#pragma unroll
    for (int e = 1; e < 8; ++e) m = fmaxf(m, lg[e]);
#pragma unroll
    for (int off = 1; off <= 8; off <<= 1) m = fmaxf(m, __shfl_xor(m, off));

    float ssum = 0.f;
#pragma unroll
    for (int e = 0; e < 8; ++e) { lg[e] = __expf(lg[e] - m); ssum += lg[e]; }
#pragma unroll
    for (int off = 1; off <= 8; off <<= 1) ssum += __shfl_xor(ssum, off);
    const float inv = 1.f / ssum;

#pragma unroll
    for (int e = 0; e < 8; ++e) At[wl][s * 8 + e] = lg[e] * inv;

    __syncthreads();

    // ---- phase B: out[c, h, w0+w2] = sum_kk At[w2][kk] * Vs[c][h][kk] ----
    const int w2 = tid & 63;
    const int c0 = __builtin_amdgcn_readfirstlane((tid >> 6) * 4);

    const float* __restrict__ vr0 = Vs + (size_t)(c0 + 0) * NPIX + h * W;
    const float* __restrict__ vr1 = Vs + (size_t)(c0 + 1) * NPIX + h * W;
    const float* __restrict__ vr2 = Vs + (size_t)(c0 + 2) * NPIX + h * W;
    const float* __restrict__ vr3 = Vs + (size_t)(c0 + 3) * NPIX + h * W;

    float acc[4];
#pragma unroll
    for (int j = 0; j < 4; ++j) acc[j] = 0.f;

#pragma unroll 4
    for (int kk = 0; kk < 128; kk += 4) {
        float4 a  = *(const float4*)(&At[w2][kk]);        // only LDS read
        float4 v0 = *(const float4*)(vr0 + kk);           // uniform loads
        float4 v1 = *(const float4*)(vr1 + kk);
        float4 v2 = *(const float4*)(vr2 + kk);
        float4 v3 = *(const float4*)(vr3 + kk);
        acc[0] += a.x * v0.x + a.y * v0.y + a.z * v0.z + a.w * v0.w;
        acc[1] += a.x * v1.x + a.y * v1.y + a.z * v1.z + a.w * v1.w;
        acc[2] += a.x * v2.x + a.y * v2.y + a.z * v2.z + a.w * v2.w;
        acc[3] += a.x * v3.x + a.y * v3.y + a.z * v3.z + a.w * v3.w;
    }

#pragma unroll
    for (int j = 0; j < 4; ++j)
        out[(size_t)(c0 + j) * NPIX + h * W + w0 + w2] = acc[j];
}

// ---------------------------------------------------------------------------
// Workspace: 6M floats = 24 MB used, non-overlapping:
//   qT [0,1M)  k [1M,2M)  v [2M,3M)  Sd [3M,5M)  Vs [5M,6M)
// ---------------------------------------------------------------------------
extern "C" void kernel_launch(void* const* d_in, const int* in_sizes, int n_in,
                              void* d_out, int out_size, void* d_ws, size_t ws_size,
                              hipStream_t stream)
{
    const float* x  = (const float*)d_in[0];
    const float* Wq = (const float*)d_in[1];
    const float* bq = (const float*)d_in[2];
    const float* Wk = (const float*)d_in[3];
    const float* bk = (const float*)d_in[4];
    const float* Wv = (const float*)d_in[5];
    const float* bv = (const float*)d_in[6];
    float* out = (float*)d_out;

    float* ws = (float*)d_ws;
    const size_t NQ = (size_t)C * NPIX;       // 1M floats
    const size_t NS = (size_t)H * W * W;      // 2M floats

    float* qT   = ws;
    float* k    = ws + NQ;
    float* v    = ws + 2 * NQ;
    float* Sd   = ws + 3 * NQ;
    float* Vsum = ws + 3 * NQ + NS;

    // MEASUREMENT: conv 4x and fused 4x (idempotent), mid 1x.
    k_conv<<<dim3(4 * (NPIX / 64 / 4) * 4, 4), 256, 0, stream>>>
        (x, Wq, bq, Wk, bk, Wv, bv, qT, k, v);   // 1024 blocks = 4 x 256
    k_mid<<<dim3(1536), 256, 0, stream>>>(qT, k, v, Sd, Vsum);
    k_fused<<<dim3(4 * H, 2), 1024, 0, stream>>>(Sd, Vsum, out);
}

// Round 15
// 121.784 us; speedup vs baseline: 1.4281x; 1.2735x over previous
//
#include <hip/hip_runtime.h>

static constexpr int C    = 64;
static constexpr int H    = 128;
static constexpr int W    = 128;
static constexpr int NPIX = H * W;      // 16384
static constexpr int PAD  = 3;          // WS=7 -> +-3

typedef float vf4 __attribute__((ext_vector_type(4)));   // NT-store-able

// ---------------------------------------------------------------------------
// 1) conv1x1, LDS-staged-x. [r12 exact] Tc+Tf measured ~11us combined (r14).
// ---------------------------------------------------------------------------
__global__ __launch_bounds__(256, 4) void k_conv(
    const float* __restrict__ x,
    const float* __restrict__ Wq, const float* __restrict__ bq,
    const float* __restrict__ Wk, const float* __restrict__ bk,
    const float* __restrict__ Wv, const float* __restrict__ bv,
    float* __restrict__ qT, float* __restrict__ ko, float* __restrict__ vo)
{
    __shared__ float xs[64][64];         // 16 KB
    const int tid  = threadIdx.x;
    const int lane = tid & 63;
    const int p0   = blockIdx.x * 64;
    const int p    = p0 + lane;
    const int o0   = __builtin_amdgcn_readfirstlane(
                         blockIdx.y * 16 + (tid >> 6) * 4);

#pragma unroll
    for (int r = 0; r < 4; ++r) {
        int f  = tid + r * 256;          // 0..1023
        int c  = f >> 4;                 // 16 float4 per channel row
        int i4 = (f & 15) << 2;
        *(float4*)(&xs[c][i4]) =
            *(const float4*)(x + (size_t)c * NPIX + p0 + i4);
    }
    __syncthreads();

    float aq[4], ak[4], av[4];
#pragma unroll
    for (int j = 0; j < 4; ++j) {
        aq[j] = bq[o0 + j];
        ak[j] = bk[o0 + j];
        av[j] = bv[o0 + j];
    }

#pragma unroll
    for (int c = 0; c < C; ++c) {
        const float xv = xs[c][lane];    // ds_read_b32, conflict-free
#pragma unroll
        for (int j = 0; j < 4; ++j) {
            aq[j] += Wq[(o0 + j) * C + c] * xv;   // W: wave-uniform s_load
            ak[j] += Wk[(o0 + j) * C + c] * xv;
            av[j] += Wv[(o0 + j) * C + c] * xv;
        }
    }

    vf4 qv4 = { aq[0], aq[1], aq[2], aq[3] };
    __builtin_nontemporal_store(qv4, (vf4*)(qT + (size_t)p * C + o0));
#pragma unroll
    for (int j = 0; j < 4; ++j) {
        __builtin_nontemporal_store(ak[j], ko + (size_t)(o0 + j) * NPIX + p);
        __builtin_nontemporal_store(av[j], vo + (size_t)(o0 + j) * NPIX + p);
    }
}

// ---------------------------------------------------------------------------
// 2) merged dispatch: [gram+diag] (0..1023) + [7x7 box] (1024..1535).
//    GRAM RESTRUCTURE (this round's single variable): 4-kk-per-thread with
//    CONTIGUOUS kk (kkt = tid&31 -> kk 4*kkt..+3), 8 row-groups x 3 rows.
//    K loads become float4 (64 dwordx4/thread), c-chunked 16-wide so only
//    64 VGPRs of k are live (resident, not sinkable). Per thread: 48 b128
//    q-broadcasts (was 96) for the same 768 FMA -> halves the LDS-pipe
//    serialization that the r13 PMC + instruction arithmetic identified
//    (~11.5us of gram's ~17). Sl writes: 3 x b128 (was 12 x b32).
//    Diag / box / staging unchanged.
// ---------------------------------------------------------------------------
__global__ __launch_bounds__(256, 3) void k_mid(
    const float* __restrict__ qT, const float* __restrict__ kmat,
    const float* __restrict__ v,
    float* __restrict__ Sd, float* __restrict__ Vs)
{
    __shared__ union {
        struct { float Sl[22][130]; float qs[22][64]; } g;   // 16.7 KB
        struct { float vt[22][128]; float vh[22][128]; } box; // 22.5 KB
    } u;
    const int bid = blockIdx.x;
    const int tid = threadIdx.x;

    if (bid < 1024) {
        // ----- fused row-Gram + diagonal 7-sum -----
        const int h   = bid >> 3;
        const int w0  = (bid & 7) * 16;

        // stage q rows w0-3 .. w0+18 (zero-filled outside [0,W))
        for (int i = tid; i < 22 * 16; i += 256) {
            int r  = i >> 4, c4 = (i & 15) << 2;
            int wp = w0 - 3 + r;
            float4 qv = make_float4(0.f, 0.f, 0.f, 0.f);
            if (wp >= 0 && wp < W)
                qv = *(const float4*)(qT + (size_t)(h * W + wp) * C + c4);
            *(float4*)(&u.g.qs[r][c4]) = qv;
        }
        __syncthreads();

        const int kkt = tid & 31;            // kk = 4*kkt .. 4*kkt+3
        const int g   = tid >> 5;            // 0..7 (3 rows each, 22 total)
        const float* kbase = kmat + h * W + kkt * 4;

        float4 acc0 = make_float4(0.f, 0.f, 0.f, 0.f);
        float4 acc1 = acc0, acc2 = acc0;

#pragma unroll
        for (int ch = 0; ch < 4; ++ch) {     // c-chunks of 16
            float4 ks4[16];                  // k[c][4kk], 64 VGPR live
#pragma unroll
            for (int i = 0; i < 16; ++i)
                ks4[i] = *(const float4*)(kbase + (size_t)(ch * 16 + i) * NPIX);
#pragma unroll
            for (int j = 0; j < 3; ++j) {
                const int row = g * 3 + j;   // 0..23 (skip >=22)
                if (row < 22) {
                    float4 a = (j == 0) ? acc0 : (j == 1) ? acc1 : acc2;
#pragma unroll
                    for (int i4 = 0; i4 < 4; ++i4) {
                        float4 qv = *(const float4*)(
                            &u.g.qs[row][ch * 16 + i4 * 4]);   // broadcast
                        float4 k0 = ks4[i4 * 4 + 0];
                        float4 k1 = ks4[i4 * 4 + 1];
                        float4 k2 = ks4[i4 * 4 + 2];
                        float4 k3 = ks4[i4 * 4 + 3];
                        a.x += qv.x * k0.x + qv.y * k1.x + qv.z * k2.x + qv.w * k3.x;
                        a.y += qv.x * k0.y + qv.y * k1.y + qv.z * k2.y + qv.w * k3.y;
                        a.z += qv.x * k0.z + qv.y * k1.z + qv.z * k2.z + qv.w * k3.z;
                        a.w += qv.x * k0.w + qv.y * k1.w + qv.z * k2.w + qv.w * k3.w;
                    }
                    if (j == 0) acc0 = a; else if (j == 1) acc1 = a; else acc2 = a;
                }
            }
        }
#pragma unroll
        for (int j = 0; j < 3; ++j) {
            const int row = g * 3 + j;
            if (row < 22) {
                float4 a = (j == 0) ? acc0 : (j == 1) ? acc1 : acc2;
                *(float4*)(&u.g.Sl[row][kkt * 4]) = a;
            }
        }
        __syncthreads();

        // ----- diagonal 7-sum (unchanged) -----
        const int kk  = tid & 127;
        const int wsl = tid >> 7;            // 0/1, wave-uniform
#pragma unroll
        for (int r = 0; r < 8; ++r) {
            int wl = wsl * 8 + r;            // 0..15
            float a = 0.f;
#pragma unroll
            for (int dd = -PAD; dd <= PAD; ++dd) {
                int kj = kk + dd;
                if (kj >= 0 && kj < W)
                    a += u.g.Sl[wl + 3 + dd][kj];
            }
            Sd[(size_t)(h * W + w0 + wl) * W + kk] = a;
        }
    } else {
        // ----- 7x7 box sum of v (separable in LDS, unchanged) -----
        const int b2 = bid - 1024;           // 0..511
        const int c  = b2 >> 3;              // 0..63
        const int h0 = (b2 & 7) * 16;

        for (int i = tid; i < 22 * 128; i += 256) {
            int r = i >> 7, w = i & 127;
            int h = h0 - 3 + r;
            u.box.vt[r][w] = (h >= 0 && h < H) ? v[c * NPIX + h * W + w] : 0.f;
        }
        __syncthreads();
        for (int i = tid; i < 22 * 128; i += 256) {
            int r = i >> 7, w = i & 127;
            float s = 0.f;
#pragma unroll
            for (int d = -PAD; d <= PAD; ++d) {
                int wj = w + d;
                if (wj >= 0 && wj < W) s += u.box.vt[r][wj];
            }
            u.box.vh[r][w] = s;
        }
        __syncthreads();
        for (int i = tid; i < 16 * 128; i += 256) {
            int r = i >> 7, w = i & 127;
            float s = 0.f;
#pragma unroll
            for (int d = 0; d < 7; ++d) s += u.box.vh[r + d][w];
            Vs[c * NPIX + (h0 + r) * W + w] = s;
        }
    }
}

// ---------------------------------------------------------------------------
// 3) FUSED vertical-7-sum + softmax + PV, V-from-global. [r12 exact]
// ---------------------------------------------------------------------------
__global__ __launch_bounds__(1024, 4) void k_fused(
    const float* __restrict__ Sd, const float* __restrict__ Vs,
    float* __restrict__ out)
{
    constexpr int AP = 129;          // attn LDS pitch
    __shared__ float At[64][AP];     // attn[w-local][kk], 33.0 KB

    const int h   = blockIdx.x;
    const int w0  = blockIdx.y * 64;
    const int tid = threadIdx.x;

    // ---- phase A: logits (vertical 7-sum of Sd) + softmax into LDS ----
    const int wl = tid >> 4;             // 0..63 (w within half)
    const int s  = tid & 15;             // kk-16th: kk = s*8 + e

    float4 g0 = make_float4(0.f, 0.f, 0.f, 0.f);
    float4 g1 = g0;
#pragma unroll
    for (int i = 0; i < 7; ++i) {
        int hp = h - 3 + i;              // block-uniform branch
        if (hp >= 0 && hp < H) {
            const float4* src = (const float4*)(
                Sd + (size_t)hp * NPIX + (w0 + wl) * W + s * 8);
            float4 a = src[0], b = src[1];
            g0.x += a.x; g0.y += a.y; g0.z += a.z; g0.w += a.w;
            g1.x += b.x; g1.y += b.y; g1.z += b.z; g1.w += b.w;
        }
    }

    float lg[8] = { g0.x, g0.y, g0.z, g0.w,  g1.x, g1.y, g1.z, g1.w };

    float m = lg[0];
#pragma unroll
    for (int e = 1; e < 8; ++e) m = fmaxf(m, lg[e]);
#pragma unroll
    for (int off = 1; off <= 8; off <<= 1) m = fmaxf(m, __shfl_xor(m, off));

    float ssum = 0.f;
#pragma unroll
    for (int e = 0; e < 8; ++e) { lg[e] = __expf(lg[e] - m); ssum += lg[e]; }
#pragma unroll
    for (int off = 1; off <= 8; off <<= 1) ssum += __shfl_xor(ssum, off);
    const float inv = 1.f / ssum;

#pragma unroll
    for (int e = 0; e < 8; ++e) At[wl][s * 8 + e] = lg[e] * inv;

    __syncthreads();

    // ---- phase B: out[c, h, w0+w2] = sum_kk At[w2][kk] * Vs[c][h][kk] ----
    const int w2 = tid & 63;
    const int c0 = __builtin_amdgcn_readfirstlane((tid >> 6) * 4);

    const float* __restrict__ vr0 = Vs + (size_t)(c0 + 0) * NPIX + h * W;
    const float* __restrict__ vr1 = Vs + (size_t)(c0 + 1) * NPIX + h * W;
    const float* __restrict__ vr2 = Vs + (size_t)(c0 + 2) * NPIX + h * W;
    const float* __restrict__ vr3 = Vs + (size_t)(c0 + 3) * NPIX + h * W;

    float acc[4];
#pragma unroll
    for (int j = 0; j < 4; ++j) acc[j] = 0.f;

#pragma unroll 4
    for (int kk = 0; kk < 128; kk += 4) {
        float4 a  = *(const float4*)(&At[w2][kk]);        // only LDS read
        float4 v0 = *(const float4*)(vr0 + kk);           // uniform loads
        float4 v1 = *(const float4*)(vr1 + kk);
        float4 v2 = *(const float4*)(vr2 + kk);
        float4 v3 = *(const float4*)(vr3 + kk);
        acc[0] += a.x * v0.x + a.y * v0.y + a.z * v0.z + a.w * v0.w;
        acc[1] += a.x * v1.x + a.y * v1.y + a.z * v1.z + a.w * v1.w;
        acc[2] += a.x * v2.x + a.y * v2.y + a.z * v2.z + a.w * v2.w;
        acc[3] += a.x * v3.x + a.y * v3.y + a.z * v3.z + a.w * v3.w;
    }

#pragma unroll
    for (int j = 0; j < 4; ++j)
        out[(size_t)(c0 + j) * NPIX + h * W + w0 + w2] = acc[j];
}

// ---------------------------------------------------------------------------
// Workspace: 6M floats = 24 MB used, non-overlapping:
//   qT [0,1M)  k [1M,2M)  v [2M,3M)  Sd [3M,5M)  Vs [5M,6M)
// ---------------------------------------------------------------------------
extern "C" void kernel_launch(void* const* d_in, const int* in_sizes, int n_in,
                              void* d_out, int out_size, void* d_ws, size_t ws_size,
                              hipStream_t stream)
{
    const float* x  = (const float*)d_in[0];
    const float* Wq = (const float*)d_in[1];
    const float* bq = (const float*)d_in[2];
    const float* Wk = (const float*)d_in[3];
    const float* bk = (const float*)d_in[4];
    const float* Wv = (const float*)d_in[5];
    const float* bv = (const float*)d_in[6];
    float* out = (float*)d_out;

    float* ws = (float*)d_ws;
    const size_t NQ = (size_t)C * NPIX;       // 1M floats
    const size_t NS = (size_t)H * W * W;      // 2M floats

    float* qT   = ws;
    float* k    = ws + NQ;
    float* v    = ws + 2 * NQ;
    float* Sd   = ws + 3 * NQ;
    float* Vsum = ws + 3 * NQ + NS;

    k_conv<<<dim3(NPIX / 64, 4), 256, 0, stream>>>(x, Wq, bq, Wk, bk, Wv, bv, qT, k, v);
    k_mid<<<dim3(1536), 256, 0, stream>>>(qT, k, v, Sd, Vsum);
    k_fused<<<dim3(H, 2), 1024, 0, stream>>>(Sd, Vsum, out);
}

// Round 16
// 115.998 us; speedup vs baseline: 1.4993x; 1.0499x over previous
//
#include <hip/hip_runtime.h>

static constexpr int C    = 64;
static constexpr int H    = 128;
static constexpr int W    = 128;
static constexpr int NPIX = H * W;      // 16384
static constexpr int PAD  = 3;          // WS=7 -> +-3

typedef float vf4 __attribute__((ext_vector_type(4)));   // NT-store-able

// ---------------------------------------------------------------------------
// 1) conv1x1, LDS-staged-x. [r15 exact] Tc+Tf measured ~11us combined (r14).
// ---------------------------------------------------------------------------
__global__ __launch_bounds__(256, 4) void k_conv(
    const float* __restrict__ x,
    const float* __restrict__ Wq, const float* __restrict__ bq,
    const float* __restrict__ Wk, const float* __restrict__ bk,
    const float* __restrict__ Wv, const float* __restrict__ bv,
    float* __restrict__ qT, float* __restrict__ ko, float* __restrict__ vo)
{
    __shared__ float xs[64][64];         // 16 KB
    const int tid  = threadIdx.x;
    const int lane = tid & 63;
    const int p0   = blockIdx.x * 64;
    const int p    = p0 + lane;
    const int o0   = __builtin_amdgcn_readfirstlane(
                         blockIdx.y * 16 + (tid >> 6) * 4);

#pragma unroll
    for (int r = 0; r < 4; ++r) {
        int f  = tid + r * 256;          // 0..1023
        int c  = f >> 4;                 // 16 float4 per channel row
        int i4 = (f & 15) << 2;
        *(float4*)(&xs[c][i4]) =
            *(const float4*)(x + (size_t)c * NPIX + p0 + i4);
    }
    __syncthreads();

    float aq[4], ak[4], av[4];
#pragma unroll
    for (int j = 0; j < 4; ++j) {
        aq[j] = bq[o0 + j];
        ak[j] = bk[o0 + j];
        av[j] = bv[o0 + j];
    }

#pragma unroll
    for (int c = 0; c < C; ++c) {
        const float xv = xs[c][lane];    // ds_read_b32, conflict-free
#pragma unroll
        for (int j = 0; j < 4; ++j) {
            aq[j] += Wq[(o0 + j) * C + c] * xv;   // W: wave-uniform s_load
            ak[j] += Wk[(o0 + j) * C + c] * xv;
            av[j] += Wv[(o0 + j) * C + c] * xv;
        }
    }

    vf4 qv4 = { aq[0], aq[1], aq[2], aq[3] };
    __builtin_nontemporal_store(qv4, (vf4*)(qT + (size_t)p * C + o0));
#pragma unroll
    for (int j = 0; j < 4; ++j) {
        __builtin_nontemporal_store(ak[j], ko + (size_t)(o0 + j) * NPIX + p);
        __builtin_nontemporal_store(av[j], vo + (size_t)(o0 + j) * NPIX + p);
    }
}

// ---------------------------------------------------------------------------
// 2) merged dispatch: [gram+diag] (0..1023) + [7x7 box] (1024..1535).
//    THIS ROUND'S single variable: __launch_bounds__(256, 6) -> all 1536
//    blocks co-resident (6 blocks/CU, 24 waves/CU; was 3 blocks/CU, Occ 30%).
//    r13 PMC showed nothing saturated (VALU 38 / HBM 21) -> latency-bound;
//    doubling TLP halves exposed stalls. To fit the ~85-VGPR budget, gram
//    k-chunks shrink 16 -> 8 float4 (32 VGPR live; q-broadcast count
//    unchanged at 48/thread, r15's win preserved).
// ---------------------------------------------------------------------------
__global__ __launch_bounds__(256, 6) void k_mid(
    const float* __restrict__ qT, const float* __restrict__ kmat,
    const float* __restrict__ v,
    float* __restrict__ Sd, float* __restrict__ Vs)
{
    __shared__ union {
        struct { float Sl[22][130]; float qs[22][64]; } g;   // 16.7 KB
        struct { float vt[22][128]; float vh[22][128]; } box; // 22.5 KB
    } u;
    const int bid = blockIdx.x;
    const int tid = threadIdx.x;

    if (bid < 1024) {
        // ----- fused row-Gram + diagonal 7-sum -----
        const int h   = bid >> 3;
        const int w0  = (bid & 7) * 16;

        // stage q rows w0-3 .. w0+18 (zero-filled outside [0,W))
        for (int i = tid; i < 22 * 16; i += 256) {
            int r  = i >> 4, c4 = (i & 15) << 2;
            int wp = w0 - 3 + r;
            float4 qv = make_float4(0.f, 0.f, 0.f, 0.f);
            if (wp >= 0 && wp < W)
                qv = *(const float4*)(qT + (size_t)(h * W + wp) * C + c4);
            *(float4*)(&u.g.qs[r][c4]) = qv;
        }
        __syncthreads();

        const int kkt = tid & 31;            // kk = 4*kkt .. 4*kkt+3
        const int g   = tid >> 5;            // 0..7 (3 rows each, 22 total)
        const float* kbase = kmat + h * W + kkt * 4;

        float4 acc0 = make_float4(0.f, 0.f, 0.f, 0.f);
        float4 acc1 = acc0, acc2 = acc0;

#pragma unroll
        for (int ch = 0; ch < 8; ++ch) {     // c-chunks of 8 (32 VGPR live)
            float4 ks4[8];
#pragma unroll
            for (int i = 0; i < 8; ++i)
                ks4[i] = *(const float4*)(kbase + (size_t)(ch * 8 + i) * NPIX);
#pragma unroll
            for (int j = 0; j < 3; ++j) {
                const int row = g * 3 + j;   // 0..23 (skip >=22)
                if (row < 22) {
                    float4 a = (j == 0) ? acc0 : (j == 1) ? acc1 : acc2;
#pragma unroll
                    for (int i4 = 0; i4 < 2; ++i4) {
                        float4 qv = *(const float4*)(
                            &u.g.qs[row][ch * 8 + i4 * 4]);    // broadcast
                        float4 k0 = ks4[i4 * 4 + 0];
                        float4 k1 = ks4[i4 * 4 + 1];
                        float4 k2 = ks4[i4 * 4 + 2];
                        float4 k3 = ks4[i4 * 4 + 3];
                        a.x += qv.x * k0.x + qv.y * k1.x + qv.z * k2.x + qv.w * k3.x;
                        a.y += qv.x * k0.y + qv.y * k1.y + qv.z * k2.y + qv.w * k3.y;
                        a.z += qv.x * k0.z + qv.y * k1.z + qv.z * k2.z + qv.w * k3.z;
                        a.w += qv.x * k0.w + qv.y * k1.w + qv.z * k2.w + qv.w * k3.w;
                    }
                    if (j == 0) acc0 = a; else if (j == 1) acc1 = a; else acc2 = a;
                }
            }
        }
#pragma unroll
        for (int j = 0; j < 3; ++j) {
            const int row = g * 3 + j;
            if (row < 22) {
                float4 a = (j == 0) ? acc0 : (j == 1) ? acc1 : acc2;
                *(float4*)(&u.g.Sl[row][kkt * 4]) = a;
            }
        }
        __syncthreads();

        // ----- diagonal 7-sum (unchanged) -----
        const int kk  = tid & 127;
        const int wsl = tid >> 7;            // 0/1, wave-uniform
#pragma unroll
        for (int r = 0; r < 8; ++r) {
            int wl = wsl * 8 + r;            // 0..15
            float a = 0.f;
#pragma unroll
            for (int dd = -PAD; dd <= PAD; ++dd) {
                int kj = kk + dd;
                if (kj >= 0 && kj < W)
                    a += u.g.Sl[wl + 3 + dd][kj];
            }
            Sd[(size_t)(h * W + w0 + wl) * W + kk] = a;
        }
    } else {
        // ----- 7x7 box sum of v (separable in LDS, unchanged) -----
        const int b2 = bid - 1024;           // 0..511
        const int c  = b2 >> 3;              // 0..63
        const int h0 = (b2 & 7) * 16;

        for (int i = tid; i < 22 * 128; i += 256) {
            int r = i >> 7, w = i & 127;
            int h = h0 - 3 + r;
            u.box.vt[r][w] = (h >= 0 && h < H) ? v[c * NPIX + h * W + w] : 0.f;
        }
        __syncthreads();
        for (int i = tid; i < 22 * 128; i += 256) {
            int r = i >> 7, w = i & 127;
            float s = 0.f;
#pragma unroll
            for (int d = -PAD; d <= PAD; ++d) {
                int wj = w + d;
                if (wj >= 0 && wj < W) s += u.box.vt[r][wj];
            }
            u.box.vh[r][w] = s;
        }
        __syncthreads();
        for (int i = tid; i < 16 * 128; i += 256) {
            int r = i >> 7, w = i & 127;
            float s = 0.f;
#pragma unroll
            for (int d = 0; d < 7; ++d) s += u.box.vh[r + d][w];
            Vs[c * NPIX + (h0 + r) * W + w] = s;
        }
    }
}

// ---------------------------------------------------------------------------
// 3) FUSED vertical-7-sum + softmax + PV, V-from-global. [r15 exact]
// ---------------------------------------------------------------------------
__global__ __launch_bounds__(1024, 4) void k_fused(
    const float* __restrict__ Sd, const float* __restrict__ Vs,
    float* __restrict__ out)
{
    constexpr int AP = 129;          // attn LDS pitch
    __shared__ float At[64][AP];     // attn[w-local][kk], 33.0 KB

    const int h   = blockIdx.x;
    const int w0  = blockIdx.y * 64;
    const int tid = threadIdx.x;

    // ---- phase A: logits (vertical 7-sum of Sd) + softmax into LDS ----
    const int wl = tid >> 4;             // 0..63 (w within half)
    const int s  = tid & 15;             // kk-16th: kk = s*8 + e

    float4 g0 = make_float4(0.f, 0.f, 0.f, 0.f);
    float4 g1 = g0;
#pragma unroll
    for (int i = 0; i < 7; ++i) {
        int hp = h - 3 + i;              // block-uniform branch
        if (hp >= 0 && hp < H) {
            const float4* src = (const float4*)(
                Sd + (size_t)hp * NPIX + (w0 + wl) * W + s * 8);
            float4 a = src[0], b = src[1];
            g0.x += a.x; g0.y += a.y; g0.z += a.z; g0.w += a.w;
            g1.x += b.x; g1.y += b.y; g1.z += b.z; g1.w += b.w;
        }
    }

    float lg[8] = { g0.x, g0.y, g0.z, g0.w,  g1.x, g1.y, g1.z, g1.w };

    float m = lg[0];
#pragma unroll
    for (int e = 1; e < 8; ++e) m = fmaxf(m, lg[e]);
#pragma unroll
    for (int off = 1; off <= 8; off <<= 1) m = fmaxf(m, __shfl_xor(m, off));

    float ssum = 0.f;
#pragma unroll
    for (int e = 0; e < 8; ++e) { lg[e] = __expf(lg[e] - m); ssum += lg[e]; }
#pragma unroll
    for (int off = 1; off <= 8; off <<= 1) ssum += __shfl_xor(ssum, off);
    const float inv = 1.f / ssum;

#pragma unroll
    for (int e = 0; e < 8; ++e) At[wl][s * 8 + e] = lg[e] * inv;

    __syncthreads();

    // ---- phase B: out[c, h, w0+w2] = sum_kk At[w2][kk] * Vs[c][h][kk] ----
    const int w2 = tid & 63;
    const int c0 = __builtin_amdgcn_readfirstlane((tid >> 6) * 4);

    const float* __restrict__ vr0 = Vs + (size_t)(c0 + 0) * NPIX + h * W;
    const float* __restrict__ vr1 = Vs + (size_t)(c0 + 1) * NPIX + h * W;
    const float* __restrict__ vr2 = Vs + (size_t)(c0 + 2) * NPIX + h * W;
    const float* __restrict__ vr3 = Vs + (size_t)(c0 + 3) * NPIX + h * W;

    float acc[4];
#pragma unroll
    for (int j = 0; j < 4; ++j) acc[j] = 0.f;

#pragma unroll 4
    for (int kk = 0; kk < 128; kk += 4) {
        float4 a  = *(const float4*)(&At[w2][kk]);        // only LDS read
        float4 v0 = *(const float4*)(vr0 + kk);           // uniform loads
        float4 v1 = *(const float4*)(vr1 + kk);
        float4 v2 = *(const float4*)(vr2 + kk);
        float4 v3 = *(const float4*)(vr3 + kk);
        acc[0] += a.x * v0.x + a.y * v0.y + a.z * v0.z + a.w * v0.w;
        acc[1] += a.x * v1.x + a.y * v1.y + a.z * v1.z + a.w * v1.w;
        acc[2] += a.x * v2.x + a.y * v2.y + a.z * v2.z + a.w * v2.w;
        acc[3] += a.x * v3.x + a.y * v3.y + a.z * v3.z + a.w * v3.w;
    }

#pragma unroll
    for (int j = 0; j < 4; ++j)
        out[(size_t)(c0 + j) * NPIX + h * W + w0 + w2] = acc[j];
}

// ---------------------------------------------------------------------------
// Workspace: 6M floats = 24 MB used, non-overlapping:
//   qT [0,1M)  k [1M,2M)  v [2M,3M)  Sd [3M,5M)  Vs [5M,6M)
// ---------------------------------------------------------------------------
extern "C" void kernel_launch(void* const* d_in, const int* in_sizes, int n_in,
                              void* d_out, int out_size, void* d_ws, size_t ws_size,
                              hipStream_t stream)
{
    const float* x  = (const float*)d_in[0];
    const float* Wq = (const float*)d_in[1];
    const float* bq = (const float*)d_in[2];
    const float* Wk = (const float*)d_in[3];
    const float* bk = (const float*)d_in[4];
    const float* Wv = (const float*)d_in[5];
    const float* bv = (const float*)d_in[6];
    float* out = (float*)d_out;

    float* ws = (float*)d_ws;
    const size_t NQ = (size_t)C * NPIX;       // 1M floats
    const size_t NS = (size_t)H * W * W;      // 2M floats

    float* qT   = ws;
    float* k    = ws + NQ;
    float* v    = ws + 2 * NQ;
    float* Sd   = ws + 3 * NQ;
    float* Vsum = ws + 3 * NQ + NS;

    k_conv<<<dim3(NPIX / 64, 4), 256, 0, stream>>>(x, Wq, bq, Wk, bk, Wv, bv, qT, k, v);
    k_mid<<<dim3(1536), 256, 0, stream>>>(qT, k, v, Sd, Vsum);
    k_fused<<<dim3(H, 2), 1024, 0, stream>>>(Sd, Vsum, out);
}

// Round 17
// 115.965 us; speedup vs baseline: 1.4998x; 1.0003x over previous
//
#include <hip/hip_runtime.h>

static constexpr int C    = 64;
static constexpr int H    = 128;
static constexpr int W    = 128;
static constexpr int NPIX = H * W;      // 16384
static constexpr int PAD  = 3;          // WS=7 -> +-3

typedef float vf2 __attribute__((ext_vector_type(2)));   // NT-store-able
typedef float vf4 __attribute__((ext_vector_type(4)));

// ---------------------------------------------------------------------------
// 1) conv1x1, LDS-staged-x, OCCUPANCY x2 (r16's proven lever applied):
//    grid (256, 8) = 2048 blocks, 8 c_out/block (2 per thread),
//    launch_bounds(256,8) -> 8 blocks/CU x 4 waves = 32 waves/CU (was 16).
//    LDS 8 x 16 KB = 128 <= 160 ✓. x staged 8x (L3-resident, ~+1us).
// ---------------------------------------------------------------------------
__global__ __launch_bounds__(256, 8) void k_conv(
    const float* __restrict__ x,
    const float* __restrict__ Wq, const float* __restrict__ bq,
    const float* __restrict__ Wk, const float* __restrict__ bk,
    const float* __restrict__ Wv, const float* __restrict__ bv,
    float* __restrict__ qT, float* __restrict__ ko, float* __restrict__ vo)
{
    __shared__ float xs[64][64];         // 16 KB
    const int tid  = threadIdx.x;
    const int lane = tid & 63;
    const int p0   = blockIdx.x * 64;
    const int p    = p0 + lane;
    const int o0   = __builtin_amdgcn_readfirstlane(
                         blockIdx.y * 8 + (tid >> 6) * 2);

#pragma unroll
    for (int r = 0; r < 4; ++r) {
        int f  = tid + r * 256;          // 0..1023
        int c  = f >> 4;                 // 16 float4 per channel row
        int i4 = (f & 15) << 2;
        *(float4*)(&xs[c][i4]) =
            *(const float4*)(x + (size_t)c * NPIX + p0 + i4);
    }
    __syncthreads();

    float aq[2], ak[2], av[2];
#pragma unroll
    for (int j = 0; j < 2; ++j) {
        aq[j] = bq[o0 + j];
        ak[j] = bk[o0 + j];
        av[j] = bv[o0 + j];
    }

#pragma unroll
    for (int c = 0; c < C; ++c) {
        const float xv = xs[c][lane];    // ds_read_b32, conflict-free
#pragma unroll
        for (int j = 0; j < 2; ++j) {
            aq[j] += Wq[(o0 + j) * C + c] * xv;   // W: wave-uniform s_load
            ak[j] += Wk[(o0 + j) * C + c] * xv;
            av[j] += Wv[(o0 + j) * C + c] * xv;
        }
    }

    vf2 q2 = { aq[0], aq[1] };
    __builtin_nontemporal_store(q2, (vf2*)(qT + (size_t)p * C + o0));
#pragma unroll
    for (int j = 0; j < 2; ++j) {
        __builtin_nontemporal_store(ak[j], ko + (size_t)(o0 + j) * NPIX + p);
        __builtin_nontemporal_store(av[j], vo + (size_t)(o0 + j) * NPIX + p);
    }
}

// ---------------------------------------------------------------------------
// 2) merged dispatch: [gram+diag] (0..1023) + [7x7 box] (1024..1535).
//    [r16 exact — (256,6), 6 blocks/CU, the round-16 win]
// ---------------------------------------------------------------------------
__global__ __launch_bounds__(256, 6) void k_mid(
    const float* __restrict__ qT, const float* __restrict__ kmat,
    const float* __restrict__ v,
    float* __restrict__ Sd, float* __restrict__ Vs)
{
    __shared__ union {
        struct { float Sl[22][130]; float qs[22][64]; } g;   // 16.7 KB
        struct { float vt[22][128]; float vh[22][128]; } box; // 22.5 KB
    } u;
    const int bid = blockIdx.x;
    const int tid = threadIdx.x;

    if (bid < 1024) {
        // ----- fused row-Gram + diagonal 7-sum -----
        const int h   = bid >> 3;
        const int w0  = (bid & 7) * 16;

        // stage q rows w0-3 .. w0+18 (zero-filled outside [0,W))
        for (int i = tid; i < 22 * 16; i += 256) {
            int r  = i >> 4, c4 = (i & 15) << 2;
            int wp = w0 - 3 + r;
            float4 qv = make_float4(0.f, 0.f, 0.f, 0.f);
            if (wp >= 0 && wp < W)
                qv = *(const float4*)(qT + (size_t)(h * W + wp) * C + c4);
            *(float4*)(&u.g.qs[r][c4]) = qv;
        }
        __syncthreads();

        const int kkt = tid & 31;            // kk = 4*kkt .. 4*kkt+3
        const int g   = tid >> 5;            // 0..7 (3 rows each, 22 total)
        const float* kbase = kmat + h * W + kkt * 4;

        float4 acc0 = make_float4(0.f, 0.f, 0.f, 0.f);
        float4 acc1 = acc0, acc2 = acc0;

#pragma unroll
        for (int ch = 0; ch < 8; ++ch) {     // c-chunks of 8 (32 VGPR live)
            float4 ks4[8];
#pragma unroll
            for (int i = 0; i < 8; ++i)
                ks4[i] = *(const float4*)(kbase + (size_t)(ch * 8 + i) * NPIX);
#pragma unroll
            for (int j = 0; j < 3; ++j) {
                const int row = g * 3 + j;   // 0..23 (skip >=22)
                if (row < 22) {
                    float4 a = (j == 0) ? acc0 : (j == 1) ? acc1 : acc2;
#pragma unroll
                    for (int i4 = 0; i4 < 2; ++i4) {
                        float4 qv = *(const float4*)(
                            &u.g.qs[row][ch * 8 + i4 * 4]);    // broadcast
                        float4 k0 = ks4[i4 * 4 + 0];
                        float4 k1 = ks4[i4 * 4 + 1];
                        float4 k2 = ks4[i4 * 4 + 2];
                        float4 k3 = ks4[i4 * 4 + 3];
                        a.x += qv.x * k0.x + qv.y * k1.x + qv.z * k2.x + qv.w * k3.x;
                        a.y += qv.x * k0.y + qv.y * k1.y + qv.z * k2.y + qv.w * k3.y;
                        a.z += qv.x * k0.z + qv.y * k1.z + qv.z * k2.z + qv.w * k3.z;
                        a.w += qv.x * k0.w + qv.y * k1.w + qv.z * k2.w + qv.w * k3.w;
                    }
                    if (j == 0) acc0 = a; else if (j == 1) acc1 = a; else acc2 = a;
                }
            }
        }
#pragma unroll
        for (int j = 0; j < 3; ++j) {
            const int row = g * 3 + j;
            if (row < 22) {
                float4 a = (j == 0) ? acc0 : (j == 1) ? acc1 : acc2;
                *(float4*)(&u.g.Sl[row][kkt * 4]) = a;
            }
        }
        __syncthreads();

        // ----- diagonal 7-sum (unchanged) -----
        const int kk  = tid & 127;
        const int wsl = tid >> 7;            // 0/1, wave-uniform
#pragma unroll
        for (int r = 0; r < 8; ++r) {
            int wl = wsl * 8 + r;            // 0..15
            float a = 0.f;
#pragma unroll
            for (int dd = -PAD; dd <= PAD; ++dd) {
                int kj = kk + dd;
                if (kj >= 0 && kj < W)
                    a += u.g.Sl[wl + 3 + dd][kj];
            }
            Sd[(size_t)(h * W + w0 + wl) * W + kk] = a;
        }
    } else {
        // ----- 7x7 box sum of v (separable in LDS, unchanged) -----
        const int b2 = bid - 1024;           // 0..511
        const int c  = b2 >> 3;              // 0..63
        const int h0 = (b2 & 7) * 16;

        for (int i = tid; i < 22 * 128; i += 256) {
            int r = i >> 7, w = i & 127;
            int h = h0 - 3 + r;
            u.box.vt[r][w] = (h >= 0 && h < H) ? v[c * NPIX + h * W + w] : 0.f;
        }
        __syncthreads();
        for (int i = tid; i < 22 * 128; i += 256) {
            int r = i >> 7, w = i & 127;
            float s = 0.f;
#pragma unroll
            for (int d = -PAD; d <= PAD; ++d) {
                int wj = w + d;
                if (wj >= 0 && wj < W) s += u.box.vt[r][wj];
            }
            u.box.vh[r][w] = s;
        }
        __syncthreads();
        for (int i = tid; i < 16 * 128; i += 256) {
            int r = i >> 7, w = i & 127;
            float s = 0.f;
#pragma unroll
            for (int d = 0; d < 7; ++d) s += u.box.vh[r + d][w];
            Vs[c * NPIX + (h0 + r) * W + w] = s;
        }
    }
}

// ---------------------------------------------------------------------------
// 3) FUSED vertical-7-sum + softmax + PV, OCCUPANCY x2 (same lever):
//    grid (128, 2, 2) = 512 blocks -> 2 blocks/CU x 16 waves = 32 waves/CU
//    (was 1 block/CU: the GRID, not resources, capped it). blockIdx.z picks
//    a 32-channel half for phase B (2 acc chains/thread); phase A (L3-hot
//    Sd reads) is computed redundantly per z — same wall time, 2x blocks.
//    launch_bounds(1024,8); LDS 33 KB x 2 = 66 <= 160 ✓. c0 stays
//    wave-uniform -> s_load V path preserved.
// ---------------------------------------------------------------------------
__global__ __launch_bounds__(1024, 8) void k_fused(
    const float* __restrict__ Sd, const float* __restrict__ Vs,
    float* __restrict__ out)
{
    constexpr int AP = 129;          // attn LDS pitch
    __shared__ float At[64][AP];     // attn[w-local][kk], 33.0 KB

    const int h   = blockIdx.x;
    const int w0  = blockIdx.y * 64;
    const int tid = threadIdx.x;

    // ---- phase A: logits (vertical 7-sum of Sd) + softmax into LDS ----
    const int wl = tid >> 4;             // 0..63 (w within half)
    const int s  = tid & 15;             // kk-16th: kk = s*8 + e

    float4 g0 = make_float4(0.f, 0.f, 0.f, 0.f);
    float4 g1 = g0;
#pragma unroll
    for (int i = 0; i < 7; ++i) {
        int hp = h - 3 + i;              // block-uniform branch
        if (hp >= 0 && hp < H) {
            const float4* src = (const float4*)(
                Sd + (size_t)hp * NPIX + (w0 + wl) * W + s * 8);
            float4 a = src[0], b = src[1];
            g0.x += a.x; g0.y += a.y; g0.z += a.z; g0.w += a.w;
            g1.x += b.x; g1.y += b.y; g1.z += b.z; g1.w += b.w;
        }
    }

    float lg[8] = { g0.x, g0.y, g0.z, g0.w,  g1.x, g1.y, g1.z, g1.w };

    float m = lg[0];
#pragma unroll
    for (int e = 1; e < 8; ++e) m = fmaxf(m, lg[e]);
#pragma unroll
    for (int off = 1; off <= 8; off <<= 1) m = fmaxf(m, __shfl_xor(m, off));

    float ssum = 0.f;
#pragma unroll
    for (int e = 0; e < 8; ++e) { lg[e] = __expf(lg[e] - m); ssum += lg[e]; }
#pragma unroll
    for (int off = 1; off <= 8; off <<= 1) ssum += __shfl_xor(ssum, off);
    const float inv = 1.f / ssum;

#pragma unroll
    for (int e = 0; e < 8; ++e) At[wl][s * 8 + e] = lg[e] * inv;

    __syncthreads();

    // ---- phase B: out[c, h, w0+w2] = sum_kk At[w2][kk] * Vs[c][h][kk]
    //      z-half of channels: c0 = z*32 + wave*2, 2 chains/thread ----
    const int w2 = tid & 63;
    const int c0 = __builtin_amdgcn_readfirstlane(
                       blockIdx.z * 32 + (tid >> 6) * 2);

    const float* __restrict__ vr0 = Vs + (size_t)(c0 + 0) * NPIX + h * W;
    const float* __restrict__ vr1 = Vs + (size_t)(c0 + 1) * NPIX + h * W;

    float acc0 = 0.f, acc1 = 0.f;

#pragma unroll 4
    for (int kk = 0; kk < 128; kk += 4) {
        float4 a  = *(const float4*)(&At[w2][kk]);        // only LDS read
        float4 v0 = *(const float4*)(vr0 + kk);           // uniform loads
        float4 v1 = *(const float4*)(vr1 + kk);
        acc0 += a.x * v0.x + a.y * v0.y + a.z * v0.z + a.w * v0.w;
        acc1 += a.x * v1.x + a.y * v1.y + a.z * v1.z + a.w * v1.w;
    }

    out[(size_t)(c0 + 0) * NPIX + h * W + w0 + w2] = acc0;
    out[(size_t)(c0 + 1) * NPIX + h * W + w0 + w2] = acc1;
}

// ---------------------------------------------------------------------------
// Workspace: 6M floats = 24 MB used, non-overlapping:
//   qT [0,1M)  k [1M,2M)  v [2M,3M)  Sd [3M,5M)  Vs [5M,6M)
// ---------------------------------------------------------------------------
extern "C" void kernel_launch(void* const* d_in, const int* in_sizes, int n_in,
                              void* d_out, int out_size, void* d_ws, size_t ws_size,
                              hipStream_t stream)
{
    const float* x  = (const float*)d_in[0];
    const float* Wq = (const float*)d_in[1];
    const float* bq = (const float*)d_in[2];
    const float* Wk = (const float*)d_in[3];
    const float* bk = (const float*)d_in[4];
    const float* Wv = (const float*)d_in[5];
    const float* bv = (const float*)d_in[6];
    float* out = (float*)d_out;

    float* ws = (float*)d_ws;
    const size_t NQ = (size_t)C * NPIX;       // 1M floats
    const size_t NS = (size_t)H * W * W;      // 2M floats

    float* qT   = ws;
    float* k    = ws + NQ;
    float* v    = ws + 2 * NQ;
    float* Sd   = ws + 3 * NQ;
    float* Vsum = ws + 3 * NQ + NS;

    k_conv<<<dim3(NPIX / 64, 8), 256, 0, stream>>>(x, Wq, bq, Wk, bk, Wv, bv, qT, k, v);
    k_mid<<<dim3(1536), 256, 0, stream>>>(qT, k, v, Sd, Vsum);
    k_fused<<<dim3(H, 2, 2), 1024, 0, stream>>>(Sd, Vsum, out);
}